// Round 7
// baseline (5578.542 us; speedup 1.0000x reference)
//
#include <hip/hip_runtime.h>
#include <hip/hip_bf16.h>
#include <cstdio>
#include <cstdint>

// Problem constants
#define BB 64
#define TT 512
#define II 512
#define HH 1024
#define G4H 4096   // 4*H
#define TC 256     // timesteps per chunk (2 chunks)
#define NG 4       // batch groups of 16 rows, all served by every WG

typedef __attribute__((ext_vector_type(8))) short short8b;  // 8 bf16 (4 VGPRs)
typedef __attribute__((ext_vector_type(4))) float f32x4;    // MFMA accumulator
typedef unsigned long long ull;

union U16 { uint4 u; short8b s; };

#define AT_LD32(p)   __hip_atomic_load((p), __ATOMIC_RELAXED, __HIP_MEMORY_SCOPE_AGENT)
#define AT_LD64(p)   __hip_atomic_load((p), __ATOMIC_RELAXED, __HIP_MEMORY_SCOPE_AGENT)
#define AT_ST32(p,v) __hip_atomic_store((p), (v), __ATOMIC_RELAXED, __HIP_MEMORY_SCOPE_AGENT)
#define AT_ST64(p,v) __hip_atomic_store((p), (v), __ATOMIC_RELAXED, __HIP_MEMORY_SCOPE_AGENT)

__device__ __forceinline__ ushort f2bf(float f) {
    union { float f; unsigned u; } x; x.f = f;
    unsigned r = x.u + 0x7FFFu + ((x.u >> 16) & 1u);
    return (ushort)(r >> 16);
}
__device__ __forceinline__ float bf2f(ushort b) {
    union { unsigned u; float f; } x; x.u = ((unsigned)b) << 16;
    return x.f;
}
__device__ __forceinline__ float sigm(float x) { return 1.f / (1.f + __expf(-x)); }
__device__ __forceinline__ float tanh_(float x) { return 2.f / (1.f + __expf(-2.f * x)) - 1.f; }

// ---------------- prep: f32 -> bf16 convert (x) ----------------
__global__ void conv_f32_bf16(const float* __restrict__ in, ushort* __restrict__ out, int n) {
    int i = (blockIdx.x * blockDim.x + threadIdx.x) * 4;
    int stride = gridDim.x * blockDim.x * 4;
    for (; i < n; i += stride) {
        float4 v = *(const float4*)(in + i);
        ushort4 o;
        o.x = f2bf(v.x); o.y = f2bf(v.y); o.z = f2bf(v.z); o.w = f2bf(v.w);
        *(ushort4*)(out + i) = o;
    }
}

// ---------------- prep: transpose f32 [K][1024] -> bf16 [1024][K] ----------------
__global__ void transpose_bf16(const float* __restrict__ in, ushort* __restrict__ out, int K) {
    __shared__ float tile[32][33];
    int j0 = blockIdx.x * 32;
    int k0 = blockIdx.y * 32;
    int tx = threadIdx.x, ty = threadIdx.y;  // 32 x 8
    #pragma unroll
    for (int i = 0; i < 32; i += 8)
        tile[ty + i][tx] = in[(size_t)(k0 + ty + i) * 1024 + j0 + tx];
    __syncthreads();
    #pragma unroll
    for (int i = 0; i < 32; i += 8)
        out[(size_t)(j0 + ty + i) * K + k0 + tx] = f2bf(tile[tx][ty + i]);
}

// ---------------- phase A: xU(chunk) = x(:, t0:t0+TC, :) @ [U_ig|U_f|U_c|U_o] + b ----
__global__ __launch_bounds__(256) void gemm_xu(
    const ushort* __restrict__ A, const ushort* __restrict__ Bt,
    const float* __restrict__ b0, const float* __restrict__ b1,
    const float* __restrict__ b2, const float* __restrict__ b3,
    ushort* __restrict__ C, int t0)
{
    __shared__ ushort As[128 * 64];
    __shared__ ushort Bs[128 * 64];
    const int m0 = blockIdx.x * 128;
    const int n0 = blockIdx.y * 128;
    const int tid = threadIdx.x;
    const int lane = tid & 63;
    const int wave = tid >> 6;
    const int wm = (wave >> 1) * 64;
    const int wn = (wave & 1) * 64;
    const int kgrp = lane >> 4;

    const ushort* Abase = A + ((size_t)(m0 >> 8) * TT + t0 + (m0 & 255)) * 512;

    f32x4 acc[4][4];
    #pragma unroll
    for (int i = 0; i < 4; ++i)
        #pragma unroll
        for (int j = 0; j < 4; ++j) acc[i][j] = (f32x4){0.f, 0.f, 0.f, 0.f};

    for (int k0 = 0; k0 < 512; k0 += 64) {
        __syncthreads();
        #pragma unroll
        for (int p = 0; p < 4; ++p) {
            int idx = p * 256 + tid;
            int row = idx >> 3;
            int kc  = idx & 7;
            uint4 va = *(const uint4*)(Abase + (size_t)row * 512 + k0 + kc * 8);
            uint4 vb = *(const uint4*)(Bt + (size_t)(n0 + row) * 512 + k0 + kc * 8);
            int bo = (row * 128 + kc * 16) ^ ((row & 7) << 4);
            *(uint4*)((char*)As + bo) = va;
            *(uint4*)((char*)Bs + bo) = vb;
        }
        __syncthreads();
        #pragma unroll
        for (int ks = 0; ks < 2; ++ks) {
            U16 af[4], bfr[4];
            #pragma unroll
            for (int i = 0; i < 4; ++i) {
                int row = wm + i * 16 + (lane & 15);
                int ao = (row * 128 + ks * 64 + kgrp * 16) ^ ((row & 7) << 4);
                af[i].u = *(const uint4*)((const char*)As + ao);
                int col = wn + i * 16 + (lane & 15);
                int bo = (col * 128 + ks * 64 + kgrp * 16) ^ ((col & 7) << 4);
                bfr[i].u = *(const uint4*)((const char*)Bs + bo);
            }
            #pragma unroll
            for (int i = 0; i < 4; ++i)
                #pragma unroll
                for (int j = 0; j < 4; ++j)
                    acc[i][j] = __builtin_amdgcn_mfma_f32_16x16x32_bf16(af[i].s, bfr[j].s, acc[i][j], 0, 0, 0);
        }
    }
    #pragma unroll
    for (int i = 0; i < 4; ++i) {
        #pragma unroll
        for (int j = 0; j < 4; ++j) {
            int row = m0 + wm + i * 16 + (lane >> 4) * 4;
            int col = n0 + wn + j * 16 + (lane & 15);
            int gate = col >> 10;
            const float* bp = (gate == 0) ? b0 : (gate == 1) ? b1 : (gate == 2) ? b2 : b3;
            float bias = bp[col & 1023];
            #pragma unroll
            for (int r = 0; r < 4; ++r)
                C[(size_t)(row + r) * G4H + col] = f2bf(acc[i][j][r] + bias);
        }
    }
}

// ---------------- phase B: persistent recurrent kernel, group-interleaved ----
// 64 WGs x 256 threads; WG = hidden slice (16 h-cols, 64 V-cols in LDS).
// Each WG serves ALL 4 batch groups per superstep t: the MALL round trip of
// group g hides under the other 3 groups' compute (T >= RTT + C pipelining).
// Flags: flags[g][slice] = t+1 after h(g,t+1) stored (monotonic, memset/launch).
// Poll target at step t is t (t=0 passes trivially; h_0 = 0 via memset).
// hbuf: [parity][grp][row16][1024] bf16; byte = p*131072 + g*32768 + row*2048 + col*2
__global__ __launch_bounds__(256) void lstm_rec(
    const ushort* __restrict__ xU,   // [B*TC][4096] bf16 chunk
    const ushort* __restrict__ V_t,  // [4096][1024] bf16 (V transposed)
    char* __restrict__ hb,           // h double buffer, 256 KB
    float* __restrict__ cbuf,        // [64][1024] f32
    float* __restrict__ out,         // h then c, f32
    unsigned* __restrict__ flags,    // [4][64]
    int t0)
{
    __shared__ __align__(16) ushort Vl[64 * 1024];  // 128 KB [col][k] XOR-swizzled
    __shared__ __align__(16) ushort hl[16 * 1024];  // 32 KB h tile [row][k] XOR-swizzled
    float* g_lds = (float*)hl;                      // overlay (first 4 KB) after MFMA reads

    const int slice = blockIdx.x;     // 0..63
    const int tid = threadIdx.x;
    const int lane = tid & 63;
    const int gate = tid >> 6;        // wave = gate 0..3

    // ---- stage V slice into LDS
    #pragma unroll
    for (int p = 0; p < 32; ++p) {
        int idx = p * 256 + tid;  // 0..8191
        int c  = idx >> 7;        // 0..63
        int kc = idx & 127;       // 8-elem k chunk
        int colg = (c >> 4) * 1024 + slice * 16 + (c & 15);
        uint4 v = *(const uint4*)(V_t + (size_t)colg * 1024 + kc * 8);
        int bo = (c * 2048 + kc * 16) ^ ((c & 7) << 4);
        *(uint4*)((char*)Vl + bo) = v;
    }

    const int bb = tid >> 4, jh = tid & 15;
    const int hcol = slice * 16 + jh;
    float c_reg[NG];
    #pragma unroll
    for (int g = 0; g < NG; ++g)
        c_reg[g] = (t0 == 0) ? 0.f : cbuf[(size_t)(g * 16 + bb) * 1024 + hcol];

    // MFMA fragment constants
    const int kgrp = lane >> 4;               // 0..3
    const int lrow = lane & 15;               // A row within group
    const int arow_sw = (lrow & 7) << 4;
    const int bc = gate * 16 + (lane & 15);   // Vl col for B frag
    const int bxor = (bc & 7) << 4;
    const int bo_base = bc * 2048 + kgrp * 16;

    __syncthreads();  // Vl staged

    for (int t = t0; t < t0 + TC; ++t) {
        // ---- prefetch xU operands for ALL groups (HBM latency hides under g0)
        ushort xg[NG][4];
        #pragma unroll
        for (int g = 0; g < NG; ++g) {
            size_t xb = ((size_t)(g * 16 + bb) * TC + (t - t0)) * G4H + hcol;
            xg[g][0] = xU[xb];        xg[g][1] = xU[xb + 1024];
            xg[g][2] = xU[xb + 2048]; xg[g][3] = xU[xb + 3072];
        }

        #pragma unroll
        for (int g = 0; g < NG; ++g) {
            // ---- poll: all 64 producers of group g reached step t
            if (tid < 64) {
                const unsigned tgt = (unsigned)t;
                const unsigned* f = flags + g * 64;
                while (AT_LD32(&f[tid]) < tgt)
                    __builtin_amdgcn_s_sleep(1);
                asm volatile("" ::: "memory");
            }
            __syncthreads();  // B1: also orders prev slot's g_lds reads vs hl overwrite

            // ---- stage h(g,t) (32 KB contiguous) from MALL into LDS
            {
                const char* hsrc = hb + (size_t)(t & 1) * 131072 + g * 32768;
                ull vv[16];
                #pragma unroll
                for (int it = 0; it < 16; ++it)
                    vv[it] = AT_LD64((const ull*)(hsrc + (size_t)(it * 256 + tid) * 8));
                #pragma unroll
                for (int it = 0; it < 16; ++it) {
                    int q = it * 256 + tid;
                    int row = q >> 8;
                    int cb  = (q & 255) * 8;
                    *(ull*)((char*)hl + ((row * 2048 + cb) ^ ((row & 7) << 4))) = vv[it];
                }
            }
            __syncthreads();  // B2

            // ---- h(g,t) @ V slice: wave `gate` computes 16 rows x 16 cols, K=1024
            f32x4 acc0 = (f32x4){0.f,0.f,0.f,0.f}, acc1 = (f32x4){0.f,0.f,0.f,0.f};
            const char* hlb = (const char*)hl;
            #pragma unroll
            for (int ks = 0; ks < 32; ks += 2) {
                U16 a0, b0, a1, b1;
                a0.u = *(const uint4*)(hlb + ((lrow * 2048 + (ks * 4 + kgrp) * 16) ^ arow_sw));
                b0.u = *(const uint4*)((const char*)Vl + ((bo_base + ks * 64) ^ bxor));
                acc0 = __builtin_amdgcn_mfma_f32_16x16x32_bf16(a0.s, b0.s, acc0, 0, 0, 0);
                a1.u = *(const uint4*)(hlb + ((lrow * 2048 + (ks * 4 + 4 + kgrp) * 16) ^ arow_sw));
                b1.u = *(const uint4*)((const char*)Vl + ((bo_base + ks * 64 + 64) ^ bxor));
                acc1 = __builtin_amdgcn_mfma_f32_16x16x32_bf16(a1.s, b1.s, acc1, 0, 0, 0);
            }
            acc0 += acc1;
            __syncthreads();  // B3: all hl reads done (g_lds overlays hl)

            // scatter: row = (lane>>4)*4 + r, col = gate*16 + (lane&15)
            {
                int rb = (lane >> 4) * 4, col = gate * 16 + (lane & 15);
                #pragma unroll
                for (int r = 0; r < 4; ++r) g_lds[(rb + r) * 64 + col] = acc0[r];
            }
            __syncthreads();  // B4

            // ---- gates + state update (thread (bb, jh))
            {
                float gi = g_lds[bb * 64 + jh]      + bf2f(xg[g][0]);
                float gf = g_lds[bb * 64 + 16 + jh] + bf2f(xg[g][1]);
                float gc = g_lds[bb * 64 + 32 + jh] + bf2f(xg[g][2]);
                float go = g_lds[bb * 64 + 48 + jh] + bf2f(xg[g][3]);
                float ig = sigm(gi), fg = sigm(gf), ct = tanh_(gc), og = sigm(go);
                c_reg[g] = ig * ct + fg * c_reg[g];
                float h = og * tanh_(c_reg[g]);
                ushort hbf = f2bf(h);
                unsigned h1 = __shfl_down((unsigned)hbf, 1);
                unsigned h2 = __shfl_down((unsigned)hbf, 2);
                unsigned h3 = __shfl_down((unsigned)hbf, 3);
                if ((jh & 3) == 0) {   // pack 4 cols -> one 8B store
                    ull pk = (ull)hbf | ((ull)(h1 & 0xffff) << 16)
                           | ((ull)(h2 & 0xffff) << 32) | ((ull)(h3 & 0xffff) << 48);
                    AT_ST64((ull*)(hb + (size_t)((t & 1) ^ 1) * 131072 + g * 32768
                                   + bb * 2048 + (size_t)(slice * 16 + jh) * 2), pk);
                }
                if (t == TT - 1) {
                    out[(size_t)(g * 16 + bb) * 1024 + hcol] = h;
                    out[(size_t)BB * HH + (size_t)(g * 16 + bb) * 1024 + hcol] = c_reg[g];
                }
            }
            __syncthreads();  // B5: h stores drained (vmcnt) -> at MALL
            if (tid == 0) AT_ST32(flags + g * 64 + slice, (unsigned)(t + 1));
        }
    }

    if (t0 + TC < TT) {
        #pragma unroll
        for (int g = 0; g < NG; ++g)
            cbuf[(size_t)(g * 16 + bb) * 1024 + hcol] = c_reg[g];
    }
}

// ---------------- host ----------------
extern "C" void kernel_launch(void* const* d_in, const int* in_sizes, int n_in,
                              void* d_out, int out_size, void* d_ws, size_t ws_size,
                              hipStream_t stream) {
    const float* x = (const float*)d_in[0];
    const float* U[4] = {(const float*)d_in[1], (const float*)d_in[4], (const float*)d_in[7], (const float*)d_in[10]};
    const float* V[4] = {(const float*)d_in[2], (const float*)d_in[5], (const float*)d_in[8], (const float*)d_in[11]};
    const float* bias[4] = {(const float*)d_in[3], (const float*)d_in[6], (const float*)d_in[9], (const float*)d_in[12]};
    float* out = (float*)d_out;

    const size_t x_elems = (size_t)BB * TT * II;
    size_t off = 0;
    auto alloc = [&](size_t bytes) { size_t o = off; off = (off + bytes + 255) & ~(size_t)255; return o; };
    size_t o_xbf   = alloc(x_elems * 2);
    size_t o_Ut    = alloc((size_t)G4H * II * 2);
    size_t o_Vt    = alloc((size_t)G4H * HH * 2);
    size_t o_xU    = alloc((size_t)BB * TC * G4H * 2);
    size_t o_hbuf  = alloc(262144);                   // [2][4][16][1024] bf16
    size_t o_cbuf  = alloc((size_t)BB * HH * 4);
    size_t o_flags = alloc(NG * 64 * 4);
    if (ws_size < off) {
        fprintf(stderr, "kernel_launch: ws too small: need %zu have %zu\n", off, ws_size);
        return;
    }
    char* ws = (char*)d_ws;
    ushort* x_bf = (ushort*)(ws + o_xbf);
    ushort* U_t  = (ushort*)(ws + o_Ut);
    ushort* V_t  = (ushort*)(ws + o_Vt);
    ushort* xU   = (ushort*)(ws + o_xU);
    char*   hbuf = ws + o_hbuf;
    float*  cbuf = (float*)(ws + o_cbuf);
    unsigned* flags = (unsigned*)(ws + o_flags);

    // reset replay state: flags -> 0 (poll tgt t=0 passes trivially), h_0 -> 0
    hipMemsetAsync(flags, 0, NG * 64 * 4, stream);
    hipMemsetAsync(hbuf, 0, 262144, stream);

    conv_f32_bf16<<<4096, 256, 0, stream>>>(x, x_bf, (int)x_elems);

    for (int g = 0; g < 4; ++g)
        transpose_bf16<<<dim3(32, 16), dim3(32, 8), 0, stream>>>(U[g], U_t + (size_t)g * 1024 * 512, 512);
    for (int g = 0; g < 4; ++g)
        transpose_bf16<<<dim3(32, 32), dim3(32, 8), 0, stream>>>(V[g], V_t + (size_t)g * 1024 * 1024, 1024);

    for (int c = 0; c < TT / TC; ++c) {
        int t0 = c * TC;
        gemm_xu<<<dim3(128, 32), 256, 0, stream>>>(x_bf, U_t, bias[0], bias[1], bias[2], bias[3], xU, t0);
        lstm_rec<<<64, 256, 0, stream>>>(xU, V_t, hbuf, cbuf, out, flags, t0);
    }
}

// Round 8
// 5226.071 us; speedup vs baseline: 1.0674x; 1.0674x over previous
//
#include <hip/hip_runtime.h>
#include <hip/hip_bf16.h>
#include <cstdio>
#include <cstdint>

// Problem constants
#define BB 64
#define TT 512
#define II 512
#define HH 1024
#define G4H 4096   // 4*H
#define TC 256     // timesteps per chunk (2 chunks)

typedef __attribute__((ext_vector_type(8))) short short8b;  // 8 bf16 (4 VGPRs)
typedef __attribute__((ext_vector_type(4))) float f32x4;    // MFMA accumulator
typedef unsigned long long ull;

union U16 { uint4 u; short8b s; };

#define AT_LD32(p)   __hip_atomic_load((p), __ATOMIC_RELAXED, __HIP_MEMORY_SCOPE_AGENT)
#define AT_LD64(p)   __hip_atomic_load((p), __ATOMIC_RELAXED, __HIP_MEMORY_SCOPE_AGENT)
#define AT_ST32(p,v) __hip_atomic_store((p), (v), __ATOMIC_RELAXED, __HIP_MEMORY_SCOPE_AGENT)
#define AT_ST64(p,v) __hip_atomic_store((p), (v), __ATOMIC_RELAXED, __HIP_MEMORY_SCOPE_AGENT)

__device__ __forceinline__ ushort f2bf(float f) {
    union { float f; unsigned u; } x; x.f = f;
    unsigned r = x.u + 0x7FFFu + ((x.u >> 16) & 1u);
    return (ushort)(r >> 16);
}
__device__ __forceinline__ float bf2f(ushort b) {
    union { unsigned u; float f; } x; x.u = ((unsigned)b) << 16;
    return x.f;
}
__device__ __forceinline__ float sigm(float x) { return 1.f / (1.f + __expf(-x)); }
__device__ __forceinline__ float tanh_(float x) { return 2.f / (1.f + __expf(-2.f * x)) - 1.f; }

// ---------------- prep: f32 -> bf16 convert (x) ----------------
__global__ void conv_f32_bf16(const float* __restrict__ in, ushort* __restrict__ out, int n) {
    int i = (blockIdx.x * blockDim.x + threadIdx.x) * 4;
    int stride = gridDim.x * blockDim.x * 4;
    for (; i < n; i += stride) {
        float4 v = *(const float4*)(in + i);
        ushort4 o;
        o.x = f2bf(v.x); o.y = f2bf(v.y); o.z = f2bf(v.z); o.w = f2bf(v.w);
        *(ushort4*)(out + i) = o;
    }
}

// ---------------- prep: transpose f32 [K][1024] -> bf16 [1024][K] ----------------
__global__ void transpose_bf16(const float* __restrict__ in, ushort* __restrict__ out, int K) {
    __shared__ float tile[32][33];
    int j0 = blockIdx.x * 32;
    int k0 = blockIdx.y * 32;
    int tx = threadIdx.x, ty = threadIdx.y;  // 32 x 8
    #pragma unroll
    for (int i = 0; i < 32; i += 8)
        tile[ty + i][tx] = in[(size_t)(k0 + ty + i) * 1024 + j0 + tx];
    __syncthreads();
    #pragma unroll
    for (int i = 0; i < 32; i += 8)
        out[(size_t)(j0 + ty + i) * K + k0 + tx] = f2bf(tile[tx][ty + i]);
}

// ---------------- phase A: xU(chunk) = x(:, t0:t0+TC, :) @ [U_ig|U_f|U_c|U_o] + b ----
__global__ __launch_bounds__(256) void gemm_xu(
    const ushort* __restrict__ A, const ushort* __restrict__ Bt,
    const float* __restrict__ b0, const float* __restrict__ b1,
    const float* __restrict__ b2, const float* __restrict__ b3,
    ushort* __restrict__ C, int t0)
{
    __shared__ ushort As[128 * 64];
    __shared__ ushort Bs[128 * 64];
    const int m0 = blockIdx.x * 128;
    const int n0 = blockIdx.y * 128;
    const int tid = threadIdx.x;
    const int lane = tid & 63;
    const int wave = tid >> 6;
    const int wm = (wave >> 1) * 64;
    const int wn = (wave & 1) * 64;
    const int kgrp = lane >> 4;

    const ushort* Abase = A + ((size_t)(m0 >> 8) * TT + t0 + (m0 & 255)) * 512;

    f32x4 acc[4][4];
    #pragma unroll
    for (int i = 0; i < 4; ++i)
        #pragma unroll
        for (int j = 0; j < 4; ++j) acc[i][j] = (f32x4){0.f, 0.f, 0.f, 0.f};

    for (int k0 = 0; k0 < 512; k0 += 64) {
        __syncthreads();
        #pragma unroll
        for (int p = 0; p < 4; ++p) {
            int idx = p * 256 + tid;
            int row = idx >> 3;
            int kc  = idx & 7;
            uint4 va = *(const uint4*)(Abase + (size_t)row * 512 + k0 + kc * 8);
            uint4 vb = *(const uint4*)(Bt + (size_t)(n0 + row) * 512 + k0 + kc * 8);
            int bo = (row * 128 + kc * 16) ^ ((row & 7) << 4);
            *(uint4*)((char*)As + bo) = va;
            *(uint4*)((char*)Bs + bo) = vb;
        }
        __syncthreads();
        #pragma unroll
        for (int ks = 0; ks < 2; ++ks) {
            U16 af[4], bfr[4];
            #pragma unroll
            for (int i = 0; i < 4; ++i) {
                int row = wm + i * 16 + (lane & 15);
                int ao = (row * 128 + ks * 64 + kgrp * 16) ^ ((row & 7) << 4);
                af[i].u = *(const uint4*)((const char*)As + ao);
                int col = wn + i * 16 + (lane & 15);
                int bo = (col * 128 + ks * 64 + kgrp * 16) ^ ((col & 7) << 4);
                bfr[i].u = *(const uint4*)((const char*)Bs + bo);
            }
            #pragma unroll
            for (int i = 0; i < 4; ++i)
                #pragma unroll
                for (int j = 0; j < 4; ++j)
                    acc[i][j] = __builtin_amdgcn_mfma_f32_16x16x32_bf16(af[i].s, bfr[j].s, acc[i][j], 0, 0, 0);
        }
    }
    #pragma unroll
    for (int i = 0; i < 4; ++i) {
        #pragma unroll
        for (int j = 0; j < 4; ++j) {
            int row = m0 + wm + i * 16 + (lane >> 4) * 4;
            int col = n0 + wn + j * 16 + (lane & 15);
            int gate = col >> 10;
            const float* bp = (gate == 0) ? b0 : (gate == 1) ? b1 : (gate == 2) ? b2 : b3;
            float bias = bp[col & 1023];
            #pragma unroll
            for (int r = 0; r < 4; ++r)
                C[(size_t)(row + r) * G4H + col] = f2bf(acc[i][j][r] + bias);
        }
    }
}

// ---------------- phase B: persistent recurrent kernel ----------------
// 256 WGs x 256 threads = 4 batch groups (16 rows) x 64 hidden slices.
// Per step: per-wave poll of 64 producer flags -> MFMA A-fragments loaded
// DIRECTLY from the h buffer into registers (64 x 8B relaxed agent loads per
// lane, one base + imm offsets, all in flight together) -> MFMA vs LDS-resident
// V slice -> scatter to parity-double-buffered g_lds -> gates -> packed 8B h
// store -> barrier(drain) -> flag. Only 2 barriers per step; no h LDS tile.
// hbuf: [parity][grp][row16][1024] bf16; byte = p*131072 + g*32768 + row*2048 + col*2
// flags[g][slice] = t+1 after h(t+1) stored (monotonic; memset once per launch;
// poll target at step t is t, so t=0 passes on zeroed flags and h_0 = 0).
__global__ __launch_bounds__(256, 1) void lstm_rec(
    const ushort* __restrict__ xU,   // [B*TC][4096] bf16 chunk
    const ushort* __restrict__ V_t,  // [4096][1024] bf16 (V transposed)
    char* __restrict__ hb,           // h double buffer, 256 KB
    float* __restrict__ cbuf,        // [64][1024] f32
    float* __restrict__ out,         // h then c, f32
    unsigned* __restrict__ flags,    // [4][64]
    int t0)
{
    __shared__ __align__(16) ushort Vl[64 * 1024];  // 128 KB [col][k] XOR-swizzled
    __shared__ float g_lds[2][16][64];              // 8 KB, parity double buffer

    const int wgid = blockIdx.x;
    const int grp = wgid >> 6;        // batch group: rows grp*16..+16
    const int slice = wgid & 63;      // h-col slice: cols slice*16..+16
    const int tid = threadIdx.x;
    const int lane = tid & 63;
    const int gate = tid >> 6;        // wave = gate 0..3

    // ---- stage V slice into LDS
    #pragma unroll
    for (int p = 0; p < 32; ++p) {
        int idx = p * 256 + tid;  // 0..8191
        int c  = idx >> 7;        // 0..63
        int kc = idx & 127;       // 8-elem k chunk
        int colg = (c >> 4) * 1024 + slice * 16 + (c & 15);
        uint4 v = *(const uint4*)(V_t + (size_t)colg * 1024 + kc * 8);
        int bo = (c * 2048 + kc * 16) ^ ((c & 7) << 4);
        *(uint4*)((char*)Vl + bo) = v;
    }

    const int bb = tid >> 4, jh = tid & 15;
    const int hcol = slice * 16 + jh;
    const int growf = grp * 16 + bb;
    float c_reg = (t0 == 0) ? 0.f : cbuf[(size_t)growf * 1024 + hcol];

    // MFMA fragment constants
    const int kgrp = lane >> 4;               // 0..3
    const int lrow = lane & 15;               // A row within group
    const int bc = gate * 16 + (lane & 15);   // Vl col for B frag
    const int bxor = (bc & 7) << 4;
    const int bo_base = bc * 2048 + kgrp * 16;

    __syncthreads();  // Vl staged

    for (int t = t0; t < t0 + TC; ++t) {
        // prefetch xU operands (plain cached loads; hide HBM latency under poll)
        size_t xbase = ((size_t)growf * TC + (t - t0)) * G4H + hcol;
        ushort xi = xU[xbase], xf = xU[xbase + 1024], xc = xU[xbase + 2048], xo = xU[xbase + 3072];

        // ---- per-wave poll: all 64 producers of this group stored h(t)
        {
            const unsigned tgt = (unsigned)t;
            const unsigned* f = flags + grp * 64;
            while (!__all((int)(AT_LD32(&f[lane]) >= tgt)))
                __builtin_amdgcn_s_sleep(1);
            asm volatile("" ::: "memory");  // no A-load hoisting above the poll
        }

        // ---- A-fragments straight from MALL into registers (64 x 8B, one base)
        ull A8[64];
        {
            const char* hsrc = hb + (size_t)(t & 1) * 131072 + grp * 32768
                             + lrow * 2048 + kgrp * 16;
            #pragma unroll
            for (int q = 0; q < 64; ++q)
                A8[q] = AT_LD64((const ull*)(hsrc + (q >> 1) * 64 + (q & 1) * 8));
        }

        // ---- h(t) @ V slice: wave `gate` computes 16 rows x 16 cols, K=1024
        f32x4 acc0 = (f32x4){0.f,0.f,0.f,0.f}, acc1 = (f32x4){0.f,0.f,0.f,0.f};
        #pragma unroll
        for (int ks = 0; ks < 32; ks += 2) {
            U16 a0, b0, a1, b1;
            a0.u.x = (unsigned)A8[2 * ks];     a0.u.y = (unsigned)(A8[2 * ks] >> 32);
            a0.u.z = (unsigned)A8[2 * ks + 1]; a0.u.w = (unsigned)(A8[2 * ks + 1] >> 32);
            b0.u = *(const uint4*)((const char*)Vl + ((bo_base + ks * 64) ^ bxor));
            acc0 = __builtin_amdgcn_mfma_f32_16x16x32_bf16(a0.s, b0.s, acc0, 0, 0, 0);
            a1.u.x = (unsigned)A8[2 * ks + 2]; a1.u.y = (unsigned)(A8[2 * ks + 2] >> 32);
            a1.u.z = (unsigned)A8[2 * ks + 3]; a1.u.w = (unsigned)(A8[2 * ks + 3] >> 32);
            b1.u = *(const uint4*)((const char*)Vl + ((bo_base + ks * 64 + 64) ^ bxor));
            acc1 = __builtin_amdgcn_mfma_f32_16x16x32_bf16(a1.s, b1.s, acc1, 0, 0, 0);
        }
        acc0 += acc1;

        // scatter: row = (lane>>4)*4 + r, col = gate*16 + (lane&15)
        {
            int rb = (lane >> 4) * 4, col = gate * 16 + (lane & 15);
            #pragma unroll
            for (int r = 0; r < 4; ++r) g_lds[t & 1][rb + r][col] = acc0[r];
        }
        __syncthreads();  // B4: scatter done -> gates may read across waves

        // ---- gates + state update (thread (bb, jh))
        {
            float gi = g_lds[t & 1][bb][jh]      + bf2f(xi);
            float gf = g_lds[t & 1][bb][16 + jh] + bf2f(xf);
            float gc = g_lds[t & 1][bb][32 + jh] + bf2f(xc);
            float go = g_lds[t & 1][bb][48 + jh] + bf2f(xo);
            float ig = sigm(gi), fg = sigm(gf), ct = tanh_(gc), og = sigm(go);
            c_reg = ig * ct + fg * c_reg;
            float h = og * tanh_(c_reg);
            ushort hbf = f2bf(h);
            unsigned h1 = __shfl_down((unsigned)hbf, 1);
            unsigned h2 = __shfl_down((unsigned)hbf, 2);
            unsigned h3 = __shfl_down((unsigned)hbf, 3);
            if ((jh & 3) == 0) {   // pack 4 cols -> one 8B store
                ull pk = (ull)hbf | ((ull)(h1 & 0xffff) << 16)
                       | ((ull)(h2 & 0xffff) << 32) | ((ull)(h3 & 0xffff) << 48);
                AT_ST64((ull*)(hb + (size_t)((t & 1) ^ 1) * 131072 + grp * 32768
                               + bb * 2048 + (size_t)(slice * 16 + jh) * 2), pk);
            }
            if (t == TT - 1) {
                out[(size_t)growf * 1024 + hcol] = h;
                out[(size_t)BB * HH + (size_t)growf * 1024 + hcol] = c_reg;
            }
        }
        __syncthreads();  // B5: all waves' h stores drained (vmcnt) -> at MALL
        if (tid == 0) AT_ST32(flags + grp * 64 + slice, (unsigned)(t + 1));
    }

    if (t0 + TC < TT)
        cbuf[(size_t)growf * 1024 + hcol] = c_reg;
}

// ---------------- host ----------------
extern "C" void kernel_launch(void* const* d_in, const int* in_sizes, int n_in,
                              void* d_out, int out_size, void* d_ws, size_t ws_size,
                              hipStream_t stream) {
    const float* x = (const float*)d_in[0];
    const float* U[4] = {(const float*)d_in[1], (const float*)d_in[4], (const float*)d_in[7], (const float*)d_in[10]};
    const float* V[4] = {(const float*)d_in[2], (const float*)d_in[5], (const float*)d_in[8], (const float*)d_in[11]};
    const float* bias[4] = {(const float*)d_in[3], (const float*)d_in[6], (const float*)d_in[9], (const float*)d_in[12]};
    float* out = (float*)d_out;

    const size_t x_elems = (size_t)BB * TT * II;
    size_t off = 0;
    auto alloc = [&](size_t bytes) { size_t o = off; off = (off + bytes + 255) & ~(size_t)255; return o; };
    size_t o_xbf   = alloc(x_elems * 2);
    size_t o_Ut    = alloc((size_t)G4H * II * 2);
    size_t o_Vt    = alloc((size_t)G4H * HH * 2);
    size_t o_xU    = alloc((size_t)BB * TC * G4H * 2);
    size_t o_hbuf  = alloc(262144);                   // [2][4][16][1024] bf16
    size_t o_cbuf  = alloc((size_t)BB * HH * 4);
    size_t o_flags = alloc(4 * 64 * 4);
    if (ws_size < off) {
        fprintf(stderr, "kernel_launch: ws too small: need %zu have %zu\n", off, ws_size);
        return;
    }
    char* ws = (char*)d_ws;
    ushort* x_bf = (ushort*)(ws + o_xbf);
    ushort* U_t  = (ushort*)(ws + o_Ut);
    ushort* V_t  = (ushort*)(ws + o_Vt);
    ushort* xU   = (ushort*)(ws + o_xU);
    char*   hbuf = ws + o_hbuf;
    float*  cbuf = (float*)(ws + o_cbuf);
    unsigned* flags = (unsigned*)(ws + o_flags);

    // reset replay state: flags -> 0 (poll tgt t=0 passes trivially), h_0 -> 0
    hipMemsetAsync(flags, 0, 4 * 64 * 4, stream);
    hipMemsetAsync(hbuf, 0, 262144, stream);

    conv_f32_bf16<<<4096, 256, 0, stream>>>(x, x_bf, (int)x_elems);

    for (int g = 0; g < 4; ++g)
        transpose_bf16<<<dim3(32, 16), dim3(32, 8), 0, stream>>>(U[g], U_t + (size_t)g * 1024 * 512, 512);
    for (int g = 0; g < 4; ++g)
        transpose_bf16<<<dim3(32, 32), dim3(32, 8), 0, stream>>>(V[g], V_t + (size_t)g * 1024 * 1024, 1024);

    for (int c = 0; c < TT / TC; ++c) {
        int t0 = c * TC;
        gemm_xu<<<dim3(128, 32), 256, 0, stream>>>(x_bf, U_t, bias[0], bias[1], bias[2], bias[3], xU, t0);
        lstm_rec<<<256, 256, 0, stream>>>(xU, V_t, hbuf, cbuf, out, flags, t0);
    }
}

// Round 9
// 3981.236 us; speedup vs baseline: 1.4012x; 1.3127x over previous
//
#include <hip/hip_runtime.h>
#include <hip/hip_bf16.h>
#include <cstdio>
#include <cstdint>

// Problem constants
#define BB 64
#define TT 512
#define II 512
#define HH 1024
#define G4H 4096   // 4*H
#define TC 256     // timesteps per chunk (2 chunks)

typedef __attribute__((ext_vector_type(8))) short short8b;  // 8 bf16 (4 VGPRs)
typedef __attribute__((ext_vector_type(4))) float f32x4;    // MFMA accumulator
typedef unsigned long long ull;

union U16 { uint4 u; short8b s; };

#define AT_LD32(p)   __hip_atomic_load((p), __ATOMIC_RELAXED, __HIP_MEMORY_SCOPE_AGENT)
#define AT_LD64(p)   __hip_atomic_load((p), __ATOMIC_RELAXED, __HIP_MEMORY_SCOPE_AGENT)
#define AT_ST32(p,v) __hip_atomic_store((p), (v), __ATOMIC_RELAXED, __HIP_MEMORY_SCOPE_AGENT)
#define AT_ST64(p,v) __hip_atomic_store((p), (v), __ATOMIC_RELAXED, __HIP_MEMORY_SCOPE_AGENT)

__device__ __forceinline__ ushort f2bf(float f) {
    union { float f; unsigned u; } x; x.f = f;
    unsigned r = x.u + 0x7FFFu + ((x.u >> 16) & 1u);
    return (ushort)(r >> 16);
}
__device__ __forceinline__ float bf2f(ushort b) {
    union { unsigned u; float f; } x; x.u = ((unsigned)b) << 16;
    return x.f;
}
__device__ __forceinline__ float sigm(float x) { return 1.f / (1.f + __expf(-x)); }
__device__ __forceinline__ float tanh_(float x) { return 2.f / (1.f + __expf(-2.f * x)) - 1.f; }

// ---------------- prep: f32 -> bf16 convert (x) ----------------
__global__ void conv_f32_bf16(const float* __restrict__ in, ushort* __restrict__ out, int n) {
    int i = (blockIdx.x * blockDim.x + threadIdx.x) * 4;
    int stride = gridDim.x * blockDim.x * 4;
    for (; i < n; i += stride) {
        float4 v = *(const float4*)(in + i);
        ushort4 o;
        o.x = f2bf(v.x); o.y = f2bf(v.y); o.z = f2bf(v.z); o.w = f2bf(v.w);
        *(ushort4*)(out + i) = o;
    }
}

// ---------------- prep: transpose f32 [K][1024] -> bf16 [1024][K] ----------------
__global__ void transpose_bf16(const float* __restrict__ in, ushort* __restrict__ out, int K) {
    __shared__ float tile[32][33];
    int j0 = blockIdx.x * 32;
    int k0 = blockIdx.y * 32;
    int tx = threadIdx.x, ty = threadIdx.y;  // 32 x 8
    #pragma unroll
    for (int i = 0; i < 32; i += 8)
        tile[ty + i][tx] = in[(size_t)(k0 + ty + i) * 1024 + j0 + tx];
    __syncthreads();
    #pragma unroll
    for (int i = 0; i < 32; i += 8)
        out[(size_t)(j0 + ty + i) * K + k0 + tx] = f2bf(tile[tx][ty + i]);
}

// ---------------- phase A: xU(chunk) = x(:, t0:t0+TC, :) @ [U_ig|U_f|U_c|U_o] + b ----
__global__ __launch_bounds__(256) void gemm_xu(
    const ushort* __restrict__ A, const ushort* __restrict__ Bt,
    const float* __restrict__ b0, const float* __restrict__ b1,
    const float* __restrict__ b2, const float* __restrict__ b3,
    ushort* __restrict__ C, int t0)
{
    __shared__ ushort As[128 * 64];
    __shared__ ushort Bs[128 * 64];
    const int m0 = blockIdx.x * 128;
    const int n0 = blockIdx.y * 128;
    const int tid = threadIdx.x;
    const int lane = tid & 63;
    const int wave = tid >> 6;
    const int wm = (wave >> 1) * 64;
    const int wn = (wave & 1) * 64;
    const int kgrp = lane >> 4;

    const ushort* Abase = A + ((size_t)(m0 >> 8) * TT + t0 + (m0 & 255)) * 512;

    f32x4 acc[4][4];
    #pragma unroll
    for (int i = 0; i < 4; ++i)
        #pragma unroll
        for (int j = 0; j < 4; ++j) acc[i][j] = (f32x4){0.f, 0.f, 0.f, 0.f};

    for (int k0 = 0; k0 < 512; k0 += 64) {
        __syncthreads();
        #pragma unroll
        for (int p = 0; p < 4; ++p) {
            int idx = p * 256 + tid;
            int row = idx >> 3;
            int kc  = idx & 7;
            uint4 va = *(const uint4*)(Abase + (size_t)row * 512 + k0 + kc * 8);
            uint4 vb = *(const uint4*)(Bt + (size_t)(n0 + row) * 512 + k0 + kc * 8);
            int bo = (row * 128 + kc * 16) ^ ((row & 7) << 4);
            *(uint4*)((char*)As + bo) = va;
            *(uint4*)((char*)Bs + bo) = vb;
        }
        __syncthreads();
        #pragma unroll
        for (int ks = 0; ks < 2; ++ks) {
            U16 af[4], bfr[4];
            #pragma unroll
            for (int i = 0; i < 4; ++i) {
                int row = wm + i * 16 + (lane & 15);
                int ao = (row * 128 + ks * 64 + kgrp * 16) ^ ((row & 7) << 4);
                af[i].u = *(const uint4*)((const char*)As + ao);
                int col = wn + i * 16 + (lane & 15);
                int bo = (col * 128 + ks * 64 + kgrp * 16) ^ ((col & 7) << 4);
                bfr[i].u = *(const uint4*)((const char*)Bs + bo);
            }
            #pragma unroll
            for (int i = 0; i < 4; ++i)
                #pragma unroll
                for (int j = 0; j < 4; ++j)
                    acc[i][j] = __builtin_amdgcn_mfma_f32_16x16x32_bf16(af[i].s, bfr[j].s, acc[i][j], 0, 0, 0);
        }
    }
    #pragma unroll
    for (int i = 0; i < 4; ++i) {
        #pragma unroll
        for (int j = 0; j < 4; ++j) {
            int row = m0 + wm + i * 16 + (lane >> 4) * 4;
            int col = n0 + wn + j * 16 + (lane & 15);
            int gate = col >> 10;
            const float* bp = (gate == 0) ? b0 : (gate == 1) ? b1 : (gate == 2) ? b2 : b3;
            float bias = bp[col & 1023];
            #pragma unroll
            for (int r = 0; r < 4; ++r)
                C[(size_t)(row + r) * G4H + col] = f2bf(acc[i][j][r] + bias);
        }
    }
}

// ---------------- phase B: persistent recurrent kernel ----------------
// 256 WGs x 256 threads = 4 batch groups (16 rows) x 64 hidden slices.
// V column order in LDS is PERMUTED so wave w computes ALL 4 gates for 4
// h-cols (mfma-col n -> gate n&3, h-col 4w+(n>>2)). After MFMA, a 2-stage
// shfl_xor 4x4 transpose within each 4-lane cluster puts the 4 gate values
// of one (row,col) into one lane's 4 regs -> gates computed wave-locally:
// NO g_lds, no scatter/gather barriers. Per-WAVE flags: each wave drains its
// own h-stores (vmcnt(0)) and fires flags[grp][w][slice]. 2 barriers/step.
// hbuf: [parity][grp][row16][1024] bf16; flags: [4 grp][4 wave][64 slice].
__global__ __launch_bounds__(256, 1) void lstm_rec(
    const ushort* __restrict__ xU,   // [B*TC][4096] bf16 chunk
    const ushort* __restrict__ V_t,  // [4096][1024] bf16 (V transposed)
    char* __restrict__ hb,           // h double buffer, 256 KB
    float* __restrict__ cbuf,        // [64][1024] f32
    float* __restrict__ out,         // h then c, f32
    unsigned* __restrict__ flags,    // [4][4][64]
    int t0)
{
    __shared__ __align__(16) ushort Vl[64 * 1024];  // 128 KB, permuted+swizzled
    __shared__ __align__(16) ushort hl[16 * 1024];  // 32 KB h tile [row][k] swizzled

    const int wgid = blockIdx.x;
    const int grp = wgid >> 6;        // batch group: rows grp*16..+16
    const int slice = wgid & 63;      // h-col slice: cols slice*16..+16
    const int tid = threadIdx.x;
    const int lane = tid & 63;
    const int w = tid >> 6;           // wave 0..3

    // ---- stage V slice into LDS.
    // LDS col c (0..63) <-> (wave = c>>4, jq = (c>>2)&3, gate = c&3):
    //   global V_t row = gate*1024 + slice*16 + 4*wave + jq
    #pragma unroll
    for (int p = 0; p < 32; ++p) {
        int idx = p * 256 + tid;  // 0..8191
        int c  = idx >> 7;        // 0..63
        int kc = idx & 127;       // 8-elem k chunk
        int colg = (c & 3) * 1024 + slice * 16 + ((c >> 4) << 2) + ((c >> 2) & 3);
        uint4 v = *(const uint4*)(V_t + (size_t)colg * 1024 + kc * 8);
        int bo = (c * 2048 + kc * 16) ^ ((c & 7) << 4);
        *(uint4*)((char*)Vl + bo) = v;
    }

    // per-lane recurrent-state mapping (from C/D layout + 4x4 transpose):
    const int myrow = (lane >> 4) * 4 + (lane & 3);    // 0..15
    const int mycol = 4 * w + ((lane >> 2) & 3);       // 0..15 within slice
    const int growf = grp * 16 + myrow;
    const int hcol = slice * 16 + mycol;
    float c_reg = (t0 == 0) ? 0.f : cbuf[(size_t)growf * 1024 + hcol];

    // MFMA fragment constants
    const int kgrp = lane >> 4;               // 0..3 (A k-group)
    const int lrow = lane & 15;               // A row
    const int arow_sw = (lrow & 7) << 4;
    const int bc = w * 16 + (lane & 15);      // Vl col for B frag
    const int bxor = (bc & 7) << 4;
    const int bo_base = bc * 2048 + kgrp * 16;

    __syncthreads();  // Vl staged

    for (int t = t0; t < t0 + TC; ++t) {
        // prefetch xU operands (issued before the poll; latency hides under it)
        size_t xbase = ((size_t)growf * TC + (t - t0)) * G4H + hcol;
        ushort xi = xU[xbase], xf = xU[xbase + 1024], xc = xU[xbase + 2048], xo = xU[xbase + 3072];

        // ---- per-wave poll: all 256 producer-wave flags of this group at step t
        {
            const unsigned tgt = (unsigned)t;
            const unsigned* f = flags + grp * 256;
            while (true) {
                unsigned v0 = AT_LD32(&f[lane]);
                unsigned v1 = AT_LD32(&f[64 + lane]);
                unsigned v2 = AT_LD32(&f[128 + lane]);
                unsigned v3 = AT_LD32(&f[192 + lane]);
                if (__all((int)(v0 >= tgt && v1 >= tgt && v2 >= tgt && v3 >= tgt))) break;
                __builtin_amdgcn_s_sleep(1);
            }
            asm volatile("" ::: "memory");
        }
        __syncthreads();  // Ba: prev-iter hl MFMA reads done; everyone past poll

        // ---- stage h(t) (32 KB contiguous) from MALL into LDS
        {
            const char* hsrc = hb + (size_t)(t & 1) * 131072 + grp * 32768;
            ull vv[16];
            #pragma unroll
            for (int it = 0; it < 16; ++it)
                vv[it] = AT_LD64((const ull*)(hsrc + (size_t)(it * 256 + tid) * 8));
            #pragma unroll
            for (int it = 0; it < 16; ++it) {
                int q = it * 256 + tid;
                int row = q >> 8;
                int cb  = (q & 255) * 8;
                *(ull*)((char*)hl + ((row * 2048 + cb) ^ ((row & 7) << 4))) = vv[it];
            }
        }
        __syncthreads();  // Bb: hl staged

        // ---- h(t) @ V slice: wave w -> 16 rows x (4 h-cols x 4 gates), K=1024
        f32x4 acc0 = (f32x4){0.f,0.f,0.f,0.f}, acc1 = (f32x4){0.f,0.f,0.f,0.f};
        const char* hlb = (const char*)hl;
        #pragma unroll
        for (int ks = 0; ks < 32; ks += 2) {
            U16 a0, b0, a1, b1;
            a0.u = *(const uint4*)(hlb + ((lrow * 2048 + (ks * 4 + kgrp) * 16) ^ arow_sw));
            b0.u = *(const uint4*)((const char*)Vl + ((bo_base + ks * 64) ^ bxor));
            acc0 = __builtin_amdgcn_mfma_f32_16x16x32_bf16(a0.s, b0.s, acc0, 0, 0, 0);
            a1.u = *(const uint4*)(hlb + ((lrow * 2048 + (ks * 4 + 4 + kgrp) * 16) ^ arow_sw));
            b1.u = *(const uint4*)((const char*)Vl + ((bo_base + ks * 64 + 64) ^ bxor));
            acc1 = __builtin_amdgcn_mfma_f32_16x16x32_bf16(a1.s, b1.s, acc1, 0, 0, 0);
        }
        float a0 = acc0[0] + acc1[0], a1 = acc0[1] + acc1[1];
        float a2 = acc0[2] + acc1[2], a3 = acc0[3] + acc1[3];

        // ---- 4x4 transpose within each 4-lane cluster (i = lane&3):
        // new a[j] of lane i = old a[j^k] of lane i^k when (i^j)&k, k = 1 then 2.
        {
            float b0 = __shfl_xor(a1, 1), b1 = __shfl_xor(a0, 1);
            float b2 = __shfl_xor(a3, 1), b3 = __shfl_xor(a2, 1);
            bool o1 = (lane & 1) != 0;
            a0 = o1 ? b0 : a0;  a1 = o1 ? a1 : b1;
            a2 = o1 ? b2 : a2;  a3 = o1 ? a3 : b3;
            b0 = __shfl_xor(a2, 2); b1 = __shfl_xor(a3, 2);
            b2 = __shfl_xor(a0, 2); b3 = __shfl_xor(a1, 2);
            bool o2 = (lane & 2) != 0;
            a0 = o2 ? b0 : a0;  a1 = o2 ? b1 : a1;
            a2 = o2 ? a2 : b2;  a3 = o2 ? a3 : b3;
        }
        // now: a0..a3 = gates (input, forget, tilded, output) of (myrow, mycol)

        // ---- gates + state update (wave-local, no barrier)
        float gi = a0 + bf2f(xi), gf = a1 + bf2f(xf);
        float gc = a2 + bf2f(xc), go = a3 + bf2f(xo);
        float ig = sigm(gi), fg = sigm(gf), ct = tanh_(gc), og = sigm(go);
        c_reg = ig * ct + fg * c_reg;
        float h = og * tanh_(c_reg);
        ushort hbf = f2bf(h);
        // pack 4 consecutive cols (jq=0..3, same row) into the jq==0 lane
        unsigned h1 = __shfl_down((unsigned)hbf, 4);
        unsigned h2 = __shfl_down((unsigned)hbf, 8);
        unsigned h3 = __shfl_down((unsigned)hbf, 12);
        if (((lane >> 2) & 3) == 0) {
            ull pk = (ull)hbf | ((ull)(h1 & 0xffff) << 16)
                   | ((ull)(h2 & 0xffff) << 32) | ((ull)(h3 & 0xffff) << 48);
            AT_ST64((ull*)(hb + (size_t)((t & 1) ^ 1) * 131072 + grp * 32768
                           + myrow * 2048 + (size_t)(slice * 16 + 4 * w) * 2), pk);
        }
        // per-wave drain of own stores, then per-wave flag (no barrier)
        asm volatile("s_waitcnt vmcnt(0)" ::: "memory");
        if (lane == 0)
            AT_ST32(flags + grp * 256 + w * 64 + slice, (unsigned)(t + 1));

        if (t == TT - 1) {  // off the critical path, after the flag
            out[(size_t)growf * 1024 + hcol] = h;
            out[(size_t)BB * HH + (size_t)growf * 1024 + hcol] = c_reg;
        }
    }

    if (t0 + TC < TT)
        cbuf[(size_t)growf * 1024 + hcol] = c_reg;
}

// ---------------- host ----------------
extern "C" void kernel_launch(void* const* d_in, const int* in_sizes, int n_in,
                              void* d_out, int out_size, void* d_ws, size_t ws_size,
                              hipStream_t stream) {
    const float* x = (const float*)d_in[0];
    const float* U[4] = {(const float*)d_in[1], (const float*)d_in[4], (const float*)d_in[7], (const float*)d_in[10]};
    const float* V[4] = {(const float*)d_in[2], (const float*)d_in[5], (const float*)d_in[8], (const float*)d_in[11]};
    const float* bias[4] = {(const float*)d_in[3], (const float*)d_in[6], (const float*)d_in[9], (const float*)d_in[12]};
    float* out = (float*)d_out;

    const size_t x_elems = (size_t)BB * TT * II;
    size_t off = 0;
    auto alloc = [&](size_t bytes) { size_t o = off; off = (off + bytes + 255) & ~(size_t)255; return o; };
    size_t o_xbf   = alloc(x_elems * 2);
    size_t o_Ut    = alloc((size_t)G4H * II * 2);
    size_t o_Vt    = alloc((size_t)G4H * HH * 2);
    size_t o_xU    = alloc((size_t)BB * TC * G4H * 2);
    size_t o_hbuf  = alloc(262144);                   // [2][4][16][1024] bf16
    size_t o_cbuf  = alloc((size_t)BB * HH * 4);
    size_t o_flags = alloc(4 * 4 * 64 * 4);           // [grp][wave][slice]
    if (ws_size < off) {
        fprintf(stderr, "kernel_launch: ws too small: need %zu have %zu\n", off, ws_size);
        return;
    }
    char* ws = (char*)d_ws;
    ushort* x_bf = (ushort*)(ws + o_xbf);
    ushort* U_t  = (ushort*)(ws + o_Ut);
    ushort* V_t  = (ushort*)(ws + o_Vt);
    ushort* xU   = (ushort*)(ws + o_xU);
    char*   hbuf = ws + o_hbuf;
    float*  cbuf = (float*)(ws + o_cbuf);
    unsigned* flags = (unsigned*)(ws + o_flags);

    // reset replay state: flags -> 0 (poll tgt t=0 passes trivially), h_0 -> 0
    hipMemsetAsync(flags, 0, 4 * 4 * 64 * 4, stream);
    hipMemsetAsync(hbuf, 0, 262144, stream);

    conv_f32_bf16<<<4096, 256, 0, stream>>>(x, x_bf, (int)x_elems);

    for (int g = 0; g < 4; ++g)
        transpose_bf16<<<dim3(32, 16), dim3(32, 8), 0, stream>>>(U[g], U_t + (size_t)g * 1024 * 512, 512);
    for (int g = 0; g < 4; ++g)
        transpose_bf16<<<dim3(32, 32), dim3(32, 8), 0, stream>>>(V[g], V_t + (size_t)g * 1024 * 1024, 1024);

    for (int c = 0; c < TT / TC; ++c) {
        int t0 = c * TC;
        gemm_xu<<<dim3(128, 32), 256, 0, stream>>>(x_bf, U_t, bias[0], bias[1], bias[2], bias[3], xU, t0);
        lstm_rec<<<256, 256, 0, stream>>>(xU, V_t, hbuf, cbuf, out, flags, t0);
    }
}

// Round 10
// 2108.789 us; speedup vs baseline: 2.6454x; 1.8879x over previous
//
#include <hip/hip_runtime.h>
#include <hip/hip_bf16.h>
#include <cstdio>
#include <cstdint>

// Problem constants
#define BB 64
#define TT 512
#define II 512
#define HH 1024
#define G4H 4096   // 4*H
#define TC 256     // timesteps per chunk (2 chunks)

typedef __attribute__((ext_vector_type(8))) short short8b;  // 8 bf16 (4 VGPRs)
typedef __attribute__((ext_vector_type(4))) float f32x4;    // MFMA accumulator
typedef unsigned long long ull;

union U16 { uint4 u; short8b s; };

#define AT_LD32(p)   __hip_atomic_load((p), __ATOMIC_RELAXED, __HIP_MEMORY_SCOPE_AGENT)
#define AT_LD64(p)   __hip_atomic_load((p), __ATOMIC_RELAXED, __HIP_MEMORY_SCOPE_AGENT)
#define AT_ST32(p,v) __hip_atomic_store((p), (v), __ATOMIC_RELAXED, __HIP_MEMORY_SCOPE_AGENT)
#define AT_ST64(p,v) __hip_atomic_store((p), (v), __ATOMIC_RELAXED, __HIP_MEMORY_SCOPE_AGENT)

__device__ __forceinline__ ushort f2bf(float f) {
    union { float f; unsigned u; } x; x.f = f;
    unsigned r = x.u + 0x7FFFu + ((x.u >> 16) & 1u);
    return (ushort)(r >> 16);
}
__device__ __forceinline__ float bf2f(ushort b) {
    union { unsigned u; float f; } x; x.u = ((unsigned)b) << 16;
    return x.f;
}
__device__ __forceinline__ float sigm(float x) { return 1.f / (1.f + __expf(-x)); }
__device__ __forceinline__ float tanh_(float x) { return 2.f / (1.f + __expf(-2.f * x)) - 1.f; }

// ---------------- prep: f32 -> bf16 convert (x) ----------------
__global__ void conv_f32_bf16(const float* __restrict__ in, ushort* __restrict__ out, int n) {
    int i = (blockIdx.x * blockDim.x + threadIdx.x) * 4;
    int stride = gridDim.x * blockDim.x * 4;
    for (; i < n; i += stride) {
        float4 v = *(const float4*)(in + i);
        ushort4 o;
        o.x = f2bf(v.x); o.y = f2bf(v.y); o.z = f2bf(v.z); o.w = f2bf(v.w);
        *(ushort4*)(out + i) = o;
    }
}

// ---------------- prep: transpose f32 [K][1024] -> bf16 [1024][K] ----------------
__global__ void transpose_bf16(const float* __restrict__ in, ushort* __restrict__ out, int K) {
    __shared__ float tile[32][33];
    int j0 = blockIdx.x * 32;
    int k0 = blockIdx.y * 32;
    int tx = threadIdx.x, ty = threadIdx.y;  // 32 x 8
    #pragma unroll
    for (int i = 0; i < 32; i += 8)
        tile[ty + i][tx] = in[(size_t)(k0 + ty + i) * 1024 + j0 + tx];
    __syncthreads();
    #pragma unroll
    for (int i = 0; i < 32; i += 8)
        out[(size_t)(j0 + ty + i) * K + k0 + tx] = f2bf(tile[tx][ty + i]);
}

// ---------------- phase A: xU(chunk) = x(:, t0:t0+TC, :) @ [U_ig|U_f|U_c|U_o] + b ----
__global__ __launch_bounds__(256) void gemm_xu(
    const ushort* __restrict__ A, const ushort* __restrict__ Bt,
    const float* __restrict__ b0, const float* __restrict__ b1,
    const float* __restrict__ b2, const float* __restrict__ b3,
    ushort* __restrict__ C, int t0)
{
    __shared__ ushort As[128 * 64];
    __shared__ ushort Bs[128 * 64];
    const int m0 = blockIdx.x * 128;
    const int n0 = blockIdx.y * 128;
    const int tid = threadIdx.x;
    const int lane = tid & 63;
    const int wave = tid >> 6;
    const int wm = (wave >> 1) * 64;
    const int wn = (wave & 1) * 64;
    const int kgrp = lane >> 4;

    const ushort* Abase = A + ((size_t)(m0 >> 8) * TT + t0 + (m0 & 255)) * 512;

    f32x4 acc[4][4];
    #pragma unroll
    for (int i = 0; i < 4; ++i)
        #pragma unroll
        for (int j = 0; j < 4; ++j) acc[i][j] = (f32x4){0.f, 0.f, 0.f, 0.f};

    for (int k0 = 0; k0 < 512; k0 += 64) {
        __syncthreads();
        #pragma unroll
        for (int p = 0; p < 4; ++p) {
            int idx = p * 256 + tid;
            int row = idx >> 3;
            int kc  = idx & 7;
            uint4 va = *(const uint4*)(Abase + (size_t)row * 512 + k0 + kc * 8);
            uint4 vb = *(const uint4*)(Bt + (size_t)(n0 + row) * 512 + k0 + kc * 8);
            int bo = (row * 128 + kc * 16) ^ ((row & 7) << 4);
            *(uint4*)((char*)As + bo) = va;
            *(uint4*)((char*)Bs + bo) = vb;
        }
        __syncthreads();
        #pragma unroll
        for (int ks = 0; ks < 2; ++ks) {
            U16 af[4], bfr[4];
            #pragma unroll
            for (int i = 0; i < 4; ++i) {
                int row = wm + i * 16 + (lane & 15);
                int ao = (row * 128 + ks * 64 + kgrp * 16) ^ ((row & 7) << 4);
                af[i].u = *(const uint4*)((const char*)As + ao);
                int col = wn + i * 16 + (lane & 15);
                int bo = (col * 128 + ks * 64 + kgrp * 16) ^ ((col & 7) << 4);
                bfr[i].u = *(const uint4*)((const char*)Bs + bo);
            }
            #pragma unroll
            for (int i = 0; i < 4; ++i)
                #pragma unroll
                for (int j = 0; j < 4; ++j)
                    acc[i][j] = __builtin_amdgcn_mfma_f32_16x16x32_bf16(af[i].s, bfr[j].s, acc[i][j], 0, 0, 0);
        }
    }
    #pragma unroll
    for (int i = 0; i < 4; ++i) {
        #pragma unroll
        for (int j = 0; j < 4; ++j) {
            int row = m0 + wm + i * 16 + (lane >> 4) * 4;
            int col = n0 + wn + j * 16 + (lane & 15);
            int gate = col >> 10;
            const float* bp = (gate == 0) ? b0 : (gate == 1) ? b1 : (gate == 2) ? b2 : b3;
            float bias = bp[col & 1023];
            #pragma unroll
            for (int r = 0; r < 4; ++r)
                C[(size_t)(row + r) * G4H + col] = f2bf(acc[i][j][r] + bias);
        }
    }
}

// ---------------- phase B: persistent recurrent kernel ----------------
// 256 WGs x 256 threads = 4 batch groups (16 rows) x 64 hidden slices.
// Comms = r4's proven scheme: 64 per-WG flags per group, single-wave poll,
// __syncthreads B5 (built-in vmcnt(0) drain) before ONE flag store per WG.
// Epilogue = r9's verified wave-local path: V columns permuted in LDS so
// wave w computes all 4 gates for 4 h-cols; 2-stage shfl_xor 4x4 transpose
// delivers the 4 gates of one (row,col) into one lane -> gates wave-local,
// no g_lds, 3 barriers/step instead of 5.
// hbuf: [parity][grp][row16][1024] bf16; flags: [4 grp][64 slice].
__global__ __launch_bounds__(256, 1) void lstm_rec(
    const ushort* __restrict__ xU,   // [B*TC][4096] bf16 chunk
    const ushort* __restrict__ V_t,  // [4096][1024] bf16 (V transposed)
    char* __restrict__ hb,           // h double buffer, 256 KB
    float* __restrict__ cbuf,        // [64][1024] f32
    float* __restrict__ out,         // h then c, f32
    unsigned* __restrict__ flags,    // [4][64]
    int t0)
{
    __shared__ __align__(16) ushort Vl[64 * 1024];  // 128 KB, permuted cols + swizzled
    __shared__ __align__(16) ushort hl[16 * 1024];  // 32 KB h tile [row][k] swizzled

    const int wgid = blockIdx.x;
    const int grp = wgid >> 6;        // batch group: rows grp*16..+16
    const int slice = wgid & 63;      // h-col slice: cols slice*16..+16
    const int tid = threadIdx.x;
    const int lane = tid & 63;
    const int w = tid >> 6;           // wave 0..3

    // ---- stage V slice into LDS.
    // LDS col c (0..63) <-> (wave = c>>4, jq = (c>>2)&3, gate = c&3):
    //   global V_t row = gate*1024 + slice*16 + 4*wave + jq
    #pragma unroll
    for (int p = 0; p < 32; ++p) {
        int idx = p * 256 + tid;  // 0..8191
        int c  = idx >> 7;        // 0..63
        int kc = idx & 127;       // 8-elem k chunk
        int colg = (c & 3) * 1024 + slice * 16 + ((c >> 4) << 2) + ((c >> 2) & 3);
        uint4 v = *(const uint4*)(V_t + (size_t)colg * 1024 + kc * 8);
        int bo = (c * 2048 + kc * 16) ^ ((c & 7) << 4);
        *(uint4*)((char*)Vl + bo) = v;
    }

    // per-lane recurrent-state mapping (C/D layout + 4x4 transpose, verified r9)
    const int myrow = (lane >> 4) * 4 + (lane & 3);    // 0..15
    const int mycol = 4 * w + ((lane >> 2) & 3);       // 0..15 within slice
    const int growf = grp * 16 + myrow;
    const int hcol = slice * 16 + mycol;
    float c_reg = (t0 == 0) ? 0.f : cbuf[(size_t)growf * 1024 + hcol];

    // MFMA fragment constants
    const int kgrp = lane >> 4;               // 0..3 (A k-group)
    const int lrow = lane & 15;               // A row
    const int arow_sw = (lrow & 7) << 4;
    const int bc = w * 16 + (lane & 15);      // Vl col for B frag
    const int bxor = (bc & 7) << 4;
    const int bo_base = bc * 2048 + kgrp * 16;

    __syncthreads();  // Vl staged

    for (int t = t0; t < t0 + TC; ++t) {
        // prefetch xU operands (issued before poll; HBM latency hides under it)
        size_t xbase = ((size_t)growf * TC + (t - t0)) * G4H + hcol;
        ushort xi = xU[xbase], xf = xU[xbase + 1024], xc = xU[xbase + 2048], xo = xU[xbase + 3072];

        // ---- single-wave poll: all 64 producers of this group stored h(t)
        if (tid < 64) {
            const unsigned tgt = (unsigned)t;
            const unsigned* f = flags + grp * 64;
            while (!__all((int)(AT_LD32(&f[tid]) >= tgt)))
                __builtin_amdgcn_s_sleep(1);
            asm volatile("" ::: "memory");
        }
        __syncthreads();  // Ba: poll done; prev-iter hl MFMA reads done

        // ---- stage h(t) (32 KB contiguous) from MALL into LDS
        {
            const char* hsrc = hb + (size_t)(t & 1) * 131072 + grp * 32768;
            ull vv[16];
            #pragma unroll
            for (int it = 0; it < 16; ++it)
                vv[it] = AT_LD64((const ull*)(hsrc + (size_t)(it * 256 + tid) * 8));
            #pragma unroll
            for (int it = 0; it < 16; ++it) {
                int q = it * 256 + tid;
                int row = q >> 8;
                int cb  = (q & 255) * 8;
                *(ull*)((char*)hl + ((row * 2048 + cb) ^ ((row & 7) << 4))) = vv[it];
            }
        }
        __syncthreads();  // Bb: hl staged

        // ---- h(t) @ V slice: wave w -> 16 rows x (4 h-cols x 4 gates), K=1024
        f32x4 acc0 = (f32x4){0.f,0.f,0.f,0.f}, acc1 = (f32x4){0.f,0.f,0.f,0.f};
        const char* hlb = (const char*)hl;
        #pragma unroll
        for (int ks = 0; ks < 32; ks += 2) {
            U16 a0, b0, a1, b1;
            a0.u = *(const uint4*)(hlb + ((lrow * 2048 + (ks * 4 + kgrp) * 16) ^ arow_sw));
            b0.u = *(const uint4*)((const char*)Vl + ((bo_base + ks * 64) ^ bxor));
            acc0 = __builtin_amdgcn_mfma_f32_16x16x32_bf16(a0.s, b0.s, acc0, 0, 0, 0);
            a1.u = *(const uint4*)(hlb + ((lrow * 2048 + (ks * 4 + 4 + kgrp) * 16) ^ arow_sw));
            b1.u = *(const uint4*)((const char*)Vl + ((bo_base + ks * 64 + 64) ^ bxor));
            acc1 = __builtin_amdgcn_mfma_f32_16x16x32_bf16(a1.s, b1.s, acc1, 0, 0, 0);
        }
        float a0 = acc0[0] + acc1[0], a1 = acc0[1] + acc1[1];
        float a2 = acc0[2] + acc1[2], a3 = acc0[3] + acc1[3];

        // ---- 4x4 transpose within each 4-lane cluster (verified r9)
        {
            float b0 = __shfl_xor(a1, 1), b1 = __shfl_xor(a0, 1);
            float b2 = __shfl_xor(a3, 1), b3 = __shfl_xor(a2, 1);
            bool o1 = (lane & 1) != 0;
            a0 = o1 ? b0 : a0;  a1 = o1 ? a1 : b1;
            a2 = o1 ? b2 : a2;  a3 = o1 ? a3 : b3;
            b0 = __shfl_xor(a2, 2); b1 = __shfl_xor(a3, 2);
            b2 = __shfl_xor(a0, 2); b3 = __shfl_xor(a1, 2);
            bool o2 = (lane & 2) != 0;
            a0 = o2 ? b0 : a0;  a1 = o2 ? b1 : a1;
            a2 = o2 ? a2 : b2;  a3 = o2 ? a3 : b3;
        }
        // a0..a3 = gates (input, forget, tilded, output) of (myrow, mycol)

        // ---- gates + state update (wave-local)
        float gi = a0 + bf2f(xi), gf = a1 + bf2f(xf);
        float gc = a2 + bf2f(xc), go = a3 + bf2f(xo);
        float ig = sigm(gi), fg = sigm(gf), ct = tanh_(gc), og = sigm(go);
        c_reg = ig * ct + fg * c_reg;
        float h = og * tanh_(c_reg);
        ushort hbf = f2bf(h);
        // pack 4 consecutive cols (jq=0..3, same row) into the jq==0 lane
        unsigned h1 = __shfl_down((unsigned)hbf, 4);
        unsigned h2 = __shfl_down((unsigned)hbf, 8);
        unsigned h3 = __shfl_down((unsigned)hbf, 12);
        if (((lane >> 2) & 3) == 0) {
            ull pk = (ull)hbf | ((ull)(h1 & 0xffff) << 16)
                   | ((ull)(h2 & 0xffff) << 32) | ((ull)(h3 & 0xffff) << 48);
            AT_ST64((ull*)(hb + (size_t)((t & 1) ^ 1) * 131072 + grp * 32768
                           + myrow * 2048 + (size_t)(slice * 16 + 4 * w) * 2), pk);
        }
        if (t == TT - 1) {
            out[(size_t)growf * 1024 + hcol] = h;
            out[(size_t)BB * HH + (size_t)growf * 1024 + hcol] = c_reg;
        }
        __syncthreads();  // B5: all waves' h stores drained (vmcnt) -> at MALL
        if (tid == 0) AT_ST32(flags + grp * 64 + slice, (unsigned)(t + 1));
    }

    if (t0 + TC < TT)
        cbuf[(size_t)growf * 1024 + hcol] = c_reg;
}

// ---------------- host ----------------
extern "C" void kernel_launch(void* const* d_in, const int* in_sizes, int n_in,
                              void* d_out, int out_size, void* d_ws, size_t ws_size,
                              hipStream_t stream) {
    const float* x = (const float*)d_in[0];
    const float* U[4] = {(const float*)d_in[1], (const float*)d_in[4], (const float*)d_in[7], (const float*)d_in[10]};
    const float* V[4] = {(const float*)d_in[2], (const float*)d_in[5], (const float*)d_in[8], (const float*)d_in[11]};
    const float* bias[4] = {(const float*)d_in[3], (const float*)d_in[6], (const float*)d_in[9], (const float*)d_in[12]};
    float* out = (float*)d_out;

    const size_t x_elems = (size_t)BB * TT * II;
    size_t off = 0;
    auto alloc = [&](size_t bytes) { size_t o = off; off = (off + bytes + 255) & ~(size_t)255; return o; };
    size_t o_xbf   = alloc(x_elems * 2);
    size_t o_Ut    = alloc((size_t)G4H * II * 2);
    size_t o_Vt    = alloc((size_t)G4H * HH * 2);
    size_t o_xU    = alloc((size_t)BB * TC * G4H * 2);
    size_t o_hbuf  = alloc(262144);                   // [2][4][16][1024] bf16
    size_t o_cbuf  = alloc((size_t)BB * HH * 4);
    size_t o_flags = alloc(4 * 64 * 4);
    if (ws_size < off) {
        fprintf(stderr, "kernel_launch: ws too small: need %zu have %zu\n", off, ws_size);
        return;
    }
    char* ws = (char*)d_ws;
    ushort* x_bf = (ushort*)(ws + o_xbf);
    ushort* U_t  = (ushort*)(ws + o_Ut);
    ushort* V_t  = (ushort*)(ws + o_Vt);
    ushort* xU   = (ushort*)(ws + o_xU);
    char*   hbuf = ws + o_hbuf;
    float*  cbuf = (float*)(ws + o_cbuf);
    unsigned* flags = (unsigned*)(ws + o_flags);

    // reset replay state: flags -> 0 (poll tgt t=0 passes trivially), h_0 -> 0
    hipMemsetAsync(flags, 0, 4 * 64 * 4, stream);
    hipMemsetAsync(hbuf, 0, 262144, stream);

    conv_f32_bf16<<<4096, 256, 0, stream>>>(x, x_bf, (int)x_elems);

    for (int g = 0; g < 4; ++g)
        transpose_bf16<<<dim3(32, 16), dim3(32, 8), 0, stream>>>(U[g], U_t + (size_t)g * 1024 * 512, 512);
    for (int g = 0; g < 4; ++g)
        transpose_bf16<<<dim3(32, 32), dim3(32, 8), 0, stream>>>(V[g], V_t + (size_t)g * 1024 * 1024, 1024);

    for (int c = 0; c < TT / TC; ++c) {
        int t0 = c * TC;
        gemm_xu<<<dim3(128, 32), 256, 0, stream>>>(x_bf, U_t, bias[0], bias[1], bias[2], bias[3], xU, t0);
        lstm_rec<<<256, 256, 0, stream>>>(xU, V_t, hbuf, cbuf, out, flags, t0);
    }
}

// Round 11
// 1893.477 us; speedup vs baseline: 2.9462x; 1.1137x over previous
//
#include <hip/hip_runtime.h>
#include <hip/hip_bf16.h>
#include <cstdio>
#include <cstdint>

// Problem constants
#define BB 64
#define TT 512
#define II 512
#define HH 1024
#define G4H 4096   // 4*H
#define TC 256     // timesteps per chunk (2 chunks)

typedef __attribute__((ext_vector_type(8))) short short8b;  // 8 bf16 (4 VGPRs)
typedef __attribute__((ext_vector_type(4))) float f32x4;    // MFMA accumulator
typedef unsigned long long ull;

union U16 { uint4 u; short8b s; };

#define AT_LD32(p)   __hip_atomic_load((p), __ATOMIC_RELAXED, __HIP_MEMORY_SCOPE_AGENT)
#define AT_LD64(p)   __hip_atomic_load((p), __ATOMIC_RELAXED, __HIP_MEMORY_SCOPE_AGENT)
#define AT_ST32(p,v) __hip_atomic_store((p), (v), __ATOMIC_RELAXED, __HIP_MEMORY_SCOPE_AGENT)
#define AT_ST64(p,v) __hip_atomic_store((p), (v), __ATOMIC_RELAXED, __HIP_MEMORY_SCOPE_AGENT)

__device__ __forceinline__ ushort f2bf(float f) {
    union { float f; unsigned u; } x; x.f = f;
    unsigned r = x.u + 0x7FFFu + ((x.u >> 16) & 1u);
    return (ushort)(r >> 16);
}
__device__ __forceinline__ float bf2f(ushort b) {
    union { unsigned u; float f; } x; x.u = ((unsigned)b) << 16;
    return x.f;
}
__device__ __forceinline__ float sigm(float x) { return 1.f / (1.f + __expf(-x)); }
__device__ __forceinline__ float tanh_(float x) { return 2.f / (1.f + __expf(-2.f * x)) - 1.f; }

// ---------------- fused prep: conv x (f32->bf16) + 8 transposes in ONE launch ----
// blocks [0,2048): conv; [2048,4096): U transposes; [4096,8192): V transposes.
__global__ __launch_bounds__(256) void prep_fused(
    const float* __restrict__ x, ushort* __restrict__ x_bf,
    const float* __restrict__ U0, const float* __restrict__ U1,
    const float* __restrict__ U2, const float* __restrict__ U3,
    ushort* __restrict__ U_t,
    const float* __restrict__ V0, const float* __restrict__ V1,
    const float* __restrict__ V2, const float* __restrict__ V3,
    ushort* __restrict__ V_t)
{
    __shared__ float tile[32][33];
    const int b = blockIdx.x;
    const int tid = threadIdx.x;
    if (b < 2048) {
        int i = (b * 256 + tid) * 4;
        const int n = BB * TT * II;
        const int stride = 2048 * 256 * 4;
        for (; i < n; i += stride) {
            float4 v = *(const float4*)(x + i);
            ushort4 o;
            o.x = f2bf(v.x); o.y = f2bf(v.y); o.z = f2bf(v.z); o.w = f2bf(v.w);
            *(ushort4*)(x_bf + i) = o;
        }
        return;
    }
    const int tx = tid & 31, ty = tid >> 5;
    const float* in; ushort* out; int K, j0, k0;
    if (b < 4096) {
        int u = b - 2048;
        int g = u >> 9, r = u & 511;
        const float* Us[4] = {U0, U1, U2, U3};
        in = Us[g]; out = U_t + (size_t)g * 1024 * 512; K = 512;
        j0 = (r & 31) * 32; k0 = (r >> 5) * 32;
    } else {
        int v = b - 4096;
        int g = v >> 10, r = v & 1023;
        const float* Vs[4] = {V0, V1, V2, V3};
        in = Vs[g]; out = V_t + (size_t)g * 1024 * 1024; K = 1024;
        j0 = (r & 31) * 32; k0 = (r >> 5) * 32;
    }
    #pragma unroll
    for (int i = 0; i < 32; i += 8)
        tile[ty + i][tx] = in[(size_t)(k0 + ty + i) * 1024 + j0 + tx];
    __syncthreads();
    #pragma unroll
    for (int i = 0; i < 32; i += 8)
        out[(size_t)(j0 + ty + i) * K + k0 + tx] = f2bf(tile[tx][ty + i]);
}

// ---------------- phase A: xU(chunk) = x(:, t0:t0+TC, :) @ [U_ig|U_f|U_c|U_o] + b ----
__global__ __launch_bounds__(256) void gemm_xu(
    const ushort* __restrict__ A, const ushort* __restrict__ Bt,
    const float* __restrict__ b0, const float* __restrict__ b1,
    const float* __restrict__ b2, const float* __restrict__ b3,
    ushort* __restrict__ C, int t0)
{
    __shared__ ushort As[128 * 64];
    __shared__ ushort Bs[128 * 64];
    const int m0 = blockIdx.x * 128;
    const int n0 = blockIdx.y * 128;
    const int tid = threadIdx.x;
    const int lane = tid & 63;
    const int wave = tid >> 6;
    const int wm = (wave >> 1) * 64;
    const int wn = (wave & 1) * 64;
    const int kgrp = lane >> 4;

    const ushort* Abase = A + ((size_t)(m0 >> 8) * TT + t0 + (m0 & 255)) * 512;

    f32x4 acc[4][4];
    #pragma unroll
    for (int i = 0; i < 4; ++i)
        #pragma unroll
        for (int j = 0; j < 4; ++j) acc[i][j] = (f32x4){0.f, 0.f, 0.f, 0.f};

    for (int k0 = 0; k0 < 512; k0 += 64) {
        __syncthreads();
        #pragma unroll
        for (int p = 0; p < 4; ++p) {
            int idx = p * 256 + tid;
            int row = idx >> 3;
            int kc  = idx & 7;
            uint4 va = *(const uint4*)(Abase + (size_t)row * 512 + k0 + kc * 8);
            uint4 vb = *(const uint4*)(Bt + (size_t)(n0 + row) * 512 + k0 + kc * 8);
            int bo = (row * 128 + kc * 16) ^ ((row & 7) << 4);
            *(uint4*)((char*)As + bo) = va;
            *(uint4*)((char*)Bs + bo) = vb;
        }
        __syncthreads();
        #pragma unroll
        for (int ks = 0; ks < 2; ++ks) {
            U16 af[4], bfr[4];
            #pragma unroll
            for (int i = 0; i < 4; ++i) {
                int row = wm + i * 16 + (lane & 15);
                int ao = (row * 128 + ks * 64 + kgrp * 16) ^ ((row & 7) << 4);
                af[i].u = *(const uint4*)((const char*)As + ao);
                int col = wn + i * 16 + (lane & 15);
                int bo = (col * 128 + ks * 64 + kgrp * 16) ^ ((col & 7) << 4);
                bfr[i].u = *(const uint4*)((const char*)Bs + bo);
            }
            #pragma unroll
            for (int i = 0; i < 4; ++i)
                #pragma unroll
                for (int j = 0; j < 4; ++j)
                    acc[i][j] = __builtin_amdgcn_mfma_f32_16x16x32_bf16(af[i].s, bfr[j].s, acc[i][j], 0, 0, 0);
        }
    }
    #pragma unroll
    for (int i = 0; i < 4; ++i) {
        #pragma unroll
        for (int j = 0; j < 4; ++j) {
            int row = m0 + wm + i * 16 + (lane >> 4) * 4;
            int col = n0 + wn + j * 16 + (lane & 15);
            int gate = col >> 10;
            const float* bp = (gate == 0) ? b0 : (gate == 1) ? b1 : (gate == 2) ? b2 : b3;
            float bias = bp[col & 1023];
            #pragma unroll
            for (int r = 0; r < 4; ++r)
                C[(size_t)(row + r) * G4H + col] = f2bf(acc[i][j][r] + bias);
        }
    }
}

// ---------------- phase B: persistent recurrent kernel ----------------
// 256 WGs x 256 threads = 4 batch groups (16 rows) x 64 hidden slices.
// r10 structure with three latency cuts:
//  (1) ALL-WAVE poll (each wave polls the 64 flags itself) -> no broadcast
//      barrier; (2) stage loads issued IMMEDIATELY after own-wave detect
//      (T14 issue-early/write-late: MALL latency overlaps detect skew);
//  (3) flags padded to one per 64B line (no hot-line store/poll contention).
// 2 barriers/step: Bb (hl staged) and B5 (h-store drain before flag).
// hbuf: [parity][grp][row16][1024] bf16; flags: [4 grp][64 slice] x 16 u32 stride.
__global__ __launch_bounds__(256, 1) void lstm_rec(
    const ushort* __restrict__ xU,   // [B*TC][4096] bf16 chunk
    const ushort* __restrict__ V_t,  // [4096][1024] bf16 (V transposed)
    char* __restrict__ hb,           // h double buffer, 256 KB
    float* __restrict__ cbuf,        // [64][1024] f32
    float* __restrict__ out,         // h then c, f32
    unsigned* __restrict__ flags,    // [4][64*16] (64B-strided flags)
    int t0)
{
    __shared__ __align__(16) ushort Vl[64 * 1024];  // 128 KB, permuted cols + swizzled
    __shared__ __align__(16) ushort hl[16 * 1024];  // 32 KB h tile [row][k] swizzled

    const int wgid = blockIdx.x;
    const int grp = wgid >> 6;        // batch group: rows grp*16..+16
    const int slice = wgid & 63;      // h-col slice: cols slice*16..+16
    const int tid = threadIdx.x;
    const int lane = tid & 63;
    const int w = tid >> 6;           // wave 0..3

    // ---- stage V slice into LDS (cols permuted: c <-> (wave=c>>4, jq=(c>>2)&3, gate=c&3))
    #pragma unroll
    for (int p = 0; p < 32; ++p) {
        int idx = p * 256 + tid;  // 0..8191
        int c  = idx >> 7;        // 0..63
        int kc = idx & 127;       // 8-elem k chunk
        int colg = (c & 3) * 1024 + slice * 16 + ((c >> 4) << 2) + ((c >> 2) & 3);
        uint4 v = *(const uint4*)(V_t + (size_t)colg * 1024 + kc * 8);
        int bo = (c * 2048 + kc * 16) ^ ((c & 7) << 4);
        *(uint4*)((char*)Vl + bo) = v;
    }

    // per-lane recurrent-state mapping (C/D layout + 4x4 transpose, verified r9/r10)
    const int myrow = (lane >> 4) * 4 + (lane & 3);    // 0..15
    const int mycol = 4 * w + ((lane >> 2) & 3);       // 0..15 within slice
    const int growf = grp * 16 + myrow;
    const int hcol = slice * 16 + mycol;
    float c_reg = (t0 == 0) ? 0.f : cbuf[(size_t)growf * 1024 + hcol];

    // MFMA fragment constants
    const int kgrp = lane >> 4;               // 0..3 (A k-group)
    const int lrow = lane & 15;               // A row
    const int arow_sw = (lrow & 7) << 4;
    const int bc = w * 16 + (lane & 15);      // Vl col for B frag
    const int bxor = (bc & 7) << 4;
    const int bo_base = bc * 2048 + kgrp * 16;

    __syncthreads();  // Vl staged

    for (int t = t0; t < t0 + TC; ++t) {
        // prefetch xU operands (issued before poll; HBM latency hides under it)
        size_t xbase = ((size_t)growf * TC + (t - t0)) * G4H + hcol;
        ushort xi = xU[xbase], xf = xU[xbase + 1024], xc = xU[xbase + 2048], xo = xU[xbase + 3072];

        // ---- all-wave poll: all 64 producers of this group stored h(t)
        {
            const unsigned tgt = (unsigned)t;
            const unsigned* f = flags + grp * 1024;
            while (!__all((int)(AT_LD32(&f[lane * 16]) >= tgt)))
                __builtin_amdgcn_s_sleep(1);
            asm volatile("" ::: "memory");
        }

        // ---- issue stage loads NOW (before any barrier): latency overlaps skew
        ull vv[16];
        {
            const char* hsrc = hb + (size_t)(t & 1) * 131072 + grp * 32768;
            #pragma unroll
            for (int it = 0; it < 16; ++it)
                vv[it] = AT_LD64((const ull*)(hsrc + (size_t)(it * 256 + tid) * 8));
        }
        // write into hl (B5 of prev iter already ordered all prev hl reads)
        {
            #pragma unroll
            for (int it = 0; it < 16; ++it) {
                int q = it * 256 + tid;
                int row = q >> 8;
                int cb  = (q & 255) * 8;
                *(ull*)((char*)hl + ((row * 2048 + cb) ^ ((row & 7) << 4))) = vv[it];
            }
        }
        __syncthreads();  // Bb: hl staged

        // ---- h(t) @ V slice: wave w -> 16 rows x (4 h-cols x 4 gates), K=1024
        f32x4 acc0 = (f32x4){0.f,0.f,0.f,0.f}, acc1 = (f32x4){0.f,0.f,0.f,0.f};
        const char* hlb = (const char*)hl;
        #pragma unroll
        for (int ks = 0; ks < 32; ks += 2) {
            U16 a0, b0, a1, b1;
            a0.u = *(const uint4*)(hlb + ((lrow * 2048 + (ks * 4 + kgrp) * 16) ^ arow_sw));
            b0.u = *(const uint4*)((const char*)Vl + ((bo_base + ks * 64) ^ bxor));
            acc0 = __builtin_amdgcn_mfma_f32_16x16x32_bf16(a0.s, b0.s, acc0, 0, 0, 0);
            a1.u = *(const uint4*)(hlb + ((lrow * 2048 + (ks * 4 + 4 + kgrp) * 16) ^ arow_sw));
            b1.u = *(const uint4*)((const char*)Vl + ((bo_base + ks * 64 + 64) ^ bxor));
            acc1 = __builtin_amdgcn_mfma_f32_16x16x32_bf16(a1.s, b1.s, acc1, 0, 0, 0);
        }
        float a0 = acc0[0] + acc1[0], a1 = acc0[1] + acc1[1];
        float a2 = acc0[2] + acc1[2], a3 = acc0[3] + acc1[3];

        // ---- 4x4 transpose within each 4-lane cluster (verified r9/r10)
        {
            float b0 = __shfl_xor(a1, 1), b1 = __shfl_xor(a0, 1);
            float b2 = __shfl_xor(a3, 1), b3 = __shfl_xor(a2, 1);
            bool o1 = (lane & 1) != 0;
            a0 = o1 ? b0 : a0;  a1 = o1 ? a1 : b1;
            a2 = o1 ? b2 : a2;  a3 = o1 ? a3 : b3;
            b0 = __shfl_xor(a2, 2); b1 = __shfl_xor(a3, 2);
            b2 = __shfl_xor(a0, 2); b3 = __shfl_xor(a1, 2);
            bool o2 = (lane & 2) != 0;
            a0 = o2 ? b0 : a0;  a1 = o2 ? b1 : a1;
            a2 = o2 ? a2 : b2;  a3 = o2 ? a3 : b3;
        }
        // a0..a3 = gates (input, forget, tilded, output) of (myrow, mycol)

        // ---- gates + state update (wave-local)
        float gi = a0 + bf2f(xi), gf = a1 + bf2f(xf);
        float gc = a2 + bf2f(xc), go = a3 + bf2f(xo);
        float ig = sigm(gi), fg = sigm(gf), ct = tanh_(gc), og = sigm(go);
        c_reg = ig * ct + fg * c_reg;
        float h = og * tanh_(c_reg);
        ushort hbf = f2bf(h);
        // pack 4 consecutive cols (jq=0..3, same row) into the jq==0 lane
        unsigned h1 = __shfl_down((unsigned)hbf, 4);
        unsigned h2 = __shfl_down((unsigned)hbf, 8);
        unsigned h3 = __shfl_down((unsigned)hbf, 12);
        if (((lane >> 2) & 3) == 0) {
            ull pk = (ull)hbf | ((ull)(h1 & 0xffff) << 16)
                   | ((ull)(h2 & 0xffff) << 32) | ((ull)(h3 & 0xffff) << 48);
            AT_ST64((ull*)(hb + (size_t)((t & 1) ^ 1) * 131072 + grp * 32768
                           + myrow * 2048 + (size_t)(slice * 16 + 4 * w) * 2), pk);
        }
        if (t == TT - 1) {
            out[(size_t)growf * 1024 + hcol] = h;
            out[(size_t)BB * HH + (size_t)growf * 1024 + hcol] = c_reg;
        }
        __syncthreads();  // B5: all waves' h stores drained (vmcnt) -> at MALL
        if (tid == 0) AT_ST32(flags + grp * 1024 + slice * 16, (unsigned)(t + 1));
    }

    if (t0 + TC < TT)
        cbuf[(size_t)growf * 1024 + hcol] = c_reg;
}

// ---------------- host ----------------
extern "C" void kernel_launch(void* const* d_in, const int* in_sizes, int n_in,
                              void* d_out, int out_size, void* d_ws, size_t ws_size,
                              hipStream_t stream) {
    const float* x = (const float*)d_in[0];
    const float* U[4] = {(const float*)d_in[1], (const float*)d_in[4], (const float*)d_in[7], (const float*)d_in[10]};
    const float* V[4] = {(const float*)d_in[2], (const float*)d_in[5], (const float*)d_in[8], (const float*)d_in[11]};
    const float* bias[4] = {(const float*)d_in[3], (const float*)d_in[6], (const float*)d_in[9], (const float*)d_in[12]};
    float* out = (float*)d_out;

    const size_t x_elems = (size_t)BB * TT * II;
    size_t off = 0;
    auto alloc = [&](size_t bytes) { size_t o = off; off = (off + bytes + 255) & ~(size_t)255; return o; };
    size_t o_xbf   = alloc(x_elems * 2);
    size_t o_Ut    = alloc((size_t)G4H * II * 2);
    size_t o_Vt    = alloc((size_t)G4H * HH * 2);
    size_t o_xU    = alloc((size_t)BB * TC * G4H * 2);
    size_t o_hbuf  = alloc(262144);                   // [2][4][16][1024] bf16
    size_t o_cbuf  = alloc((size_t)BB * HH * 4);
    size_t o_flags = alloc(4 * 64 * 64);              // 64B-strided flags, 16 KB
    if (ws_size < off) {
        fprintf(stderr, "kernel_launch: ws too small: need %zu have %zu\n", off, ws_size);
        return;
    }
    char* ws = (char*)d_ws;
    ushort* x_bf = (ushort*)(ws + o_xbf);
    ushort* U_t  = (ushort*)(ws + o_Ut);
    ushort* V_t  = (ushort*)(ws + o_Vt);
    ushort* xU   = (ushort*)(ws + o_xU);
    char*   hbuf = ws + o_hbuf;
    float*  cbuf = (float*)(ws + o_cbuf);
    unsigned* flags = (unsigned*)(ws + o_flags);

    // reset replay state: flags -> 0 (poll tgt t=0 passes trivially), h_0 -> 0
    hipMemsetAsync(flags, 0, 4 * 64 * 64, stream);
    hipMemsetAsync(hbuf, 0, 262144, stream);

    prep_fused<<<8192, 256, 0, stream>>>(x, x_bf,
        U[0], U[1], U[2], U[3], U_t,
        V[0], V[1], V[2], V[3], V_t);

    for (int c = 0; c < TT / TC; ++c) {
        int t0 = c * TC;
        gemm_xu<<<dim3(128, 32), 256, 0, stream>>>(x_bf, U_t, bias[0], bias[1], bias[2], bias[3], xU, t0);
        lstm_rec<<<256, 256, 0, stream>>>(xU, V_t, hbuf, cbuf, out, flags, t0);
    }
}